// Round 7
// baseline (383.607 us; speedup 1.0000x reference)
//
#include <hip/hip_runtime.h>
#include <hip/hip_bf16.h>
#include <math.h>

// Invariant Point Attention (AlphaFold IPA), B=1, N=512, CS=384, CZ=128,
// H=12, C=16, PQ=4, PV=8. All f32.
// Round 6: resubmission of the round-5 merged pipeline (never executed due
// to GPUAcquisitionTimeout). Audited, unchanged structure:
//   proj_gemm -> prep_points -> qkpt_gemm -> logits_k (z pass 1)
//   -> attn_apply (softmax + o + o_pt + point-finish + o_pair, z pass 2)
//   -> gemm_ksplit -> reduce_out

#define N_    512
#define CS_   384
#define INF_  100000.0f
#define EPS_  1e-8f

#define SC_QK 0.14433756729740643f   // sqrt(1/48)
#define SC_B  0.5773502691896258f    // sqrt(1/3)
#define SC_HW 0.13608276348795434f   // sqrt(1/54)

__device__ __forceinline__ float softplus_(float x) {
    return (x > 20.f) ? x : log1pf(__expf(x));
}

// ---------------------------------------------------------------------------
// Fused multi-target projection GEMM: C_t = s @ W_t + b_t for 4 targets.
// ---------------------------------------------------------------------------
__global__ __launch_bounds__(256) void proj_gemm(
    const float* __restrict__ A,
    const float* __restrict__ W0, const float* __restrict__ b0, float* __restrict__ C0, int N0,
    const float* __restrict__ W1, const float* __restrict__ b1, float* __restrict__ C1, int N1,
    const float* __restrict__ W2, const float* __restrict__ b2, float* __restrict__ C2, int N2,
    const float* __restrict__ W3, const float* __restrict__ b3, float* __restrict__ C3, int N3)
{
    const float* W; const float* bias; float* C; int Nt;
    switch (blockIdx.z) {
        case 0:  W = W0; bias = b0; C = C0; Nt = N0; break;
        case 1:  W = W1; bias = b1; C = C1; Nt = N1; break;
        case 2:  W = W2; bias = b2; C = C2; Nt = N2; break;
        default: W = W3; bias = b3; C = C3; Nt = N3; break;
    }
    const int n0 = blockIdx.y * 64;
    if (n0 >= Nt) return;
    const int m0 = blockIdx.x * 64;

    __shared__ float As[16 * 68];
    __shared__ float Bs[16 * 68];
    const int t  = threadIdx.x;
    const int tm = t & 15;
    const int tn = t >> 4;

    float acc[4][4];
    #pragma unroll
    for (int r = 0; r < 4; ++r)
        #pragma unroll
        for (int c = 0; c < 4; ++c) acc[r][c] = 0.f;

    for (int k0 = 0; k0 < CS_; k0 += 16) {
        {
            int m = t >> 2, kb = (t & 3) * 4;
            float4 a4 = *(const float4*)(A + (size_t)(m0 + m) * CS_ + k0 + kb);
            As[(kb + 0) * 68 + m] = a4.x;
            As[(kb + 1) * 68 + m] = a4.y;
            As[(kb + 2) * 68 + m] = a4.z;
            As[(kb + 3) * 68 + m] = a4.w;
        }
        {
            int kk = t >> 4, n = (t & 15) * 4;
            int gn = n0 + n;
            const float* wr = W + (size_t)(k0 + kk) * Nt;
            float4 b4;
            b4.x = (gn + 0 < Nt) ? wr[gn + 0] : 0.f;
            b4.y = (gn + 1 < Nt) ? wr[gn + 1] : 0.f;
            b4.z = (gn + 2 < Nt) ? wr[gn + 2] : 0.f;
            b4.w = (gn + 3 < Nt) ? wr[gn + 3] : 0.f;
            *(float4*)(Bs + kk * 68 + n) = b4;
        }
        __syncthreads();
        #pragma unroll
        for (int kk = 0; kk < 16; ++kk) {
            float4 a4 = *(const float4*)(As + kk * 68 + tm * 4);
            float4 b4 = *(const float4*)(Bs + kk * 68 + tn * 4);
            float am[4] = {a4.x, a4.y, a4.z, a4.w};
            float bn[4] = {b4.x, b4.y, b4.z, b4.w};
            #pragma unroll
            for (int r = 0; r < 4; ++r)
                #pragma unroll
                for (int c = 0; c < 4; ++c)
                    acc[r][c] = fmaf(am[r], bn[c], acc[r][c]);
        }
        __syncthreads();
    }
    #pragma unroll
    for (int r = 0; r < 4; ++r) {
        int gm = m0 + tm * 4 + r;
        int gn = n0 + tn * 4;
        float* cr = C + (size_t)gm * Nt;
        #pragma unroll
        for (int c = 0; c < 4; ++c)
            if (gn + c < Nt) cr[gn + c] = acc[r][c] + bias[gn + c];
    }
}

// ---------------------------------------------------------------------------
// Points + layouts for the qkpt GEMM and the AV step.
//   qp/kp[n][48pt][3]; vcat[n][512] (v 0..191 | v_pts 192..479)
//   qcat[h][n][28] = [q | qp];  kcat[h][n][28] = [k*SC_QK | kp*hw]
//   qn[h][n] = 0.5*hw*|qp|^2;   kn[h][n] = 0.5*hw*|kp|^2
// ---------------------------------------------------------------------------
__global__ __launch_bounds__(192) void prep_points(
    const float* __restrict__ lqp, const float* __restrict__ lkvp,
    const float* __restrict__ rot, const float* __restrict__ trans,
    const float* __restrict__ kvb, const float* __restrict__ q,
    const float* __restrict__ hwraw,
    float* __restrict__ qp, float* __restrict__ kp,
    float* __restrict__ vcat, float* __restrict__ qcat,
    float* __restrict__ kcat, float* __restrict__ qn, float* __restrict__ kn)
{
    const int n = blockIdx.x;
    const int t = threadIdx.x;
    const float* R = rot   + n * 9;
    const float* T = trans + n * 3;

    if (t < 48) {
        float p0 = lqp[n * 144 + t];
        float p1 = lqp[n * 144 + 48 + t];
        float p2 = lqp[n * 144 + 96 + t];
        float* d = qp + n * 144 + t * 3;
        d[0] = R[0]*p0 + R[1]*p1 + R[2]*p2 + T[0];
        d[1] = R[3]*p0 + R[4]*p1 + R[5]*p2 + T[1];
        d[2] = R[6]*p0 + R[7]*p1 + R[8]*p2 + T[2];
    } else {
        int jj = t - 48;    // 0..143
        float p0 = lkvp[n * 432 + jj];
        float p1 = lkvp[n * 432 + 144 + jj];
        float p2 = lkvp[n * 432 + 288 + jj];
        float g0 = R[0]*p0 + R[1]*p1 + R[2]*p2 + T[0];
        float g1 = R[3]*p0 + R[4]*p1 + R[5]*p2 + T[1];
        float g2 = R[6]*p0 + R[7]*p1 + R[8]*p2 + T[2];
        int h = jj / 12, idx = jj % 12;
        if (idx < 4) {
            float* d = kp + n * 144 + (h * 4 + idx) * 3;
            d[0] = g0; d[1] = g1; d[2] = g2;
        } else {
            float* d = vcat + (size_t)n * 512 + 192 + h * 24 + (idx - 4) * 3;
            d[0] = g0; d[1] = g1; d[2] = g2;
        }
    }
    vcat[(size_t)n * 512 + t] = kvb[(size_t)n * 384 + (t >> 4) * 32 + 16 + (t & 15)];
    __syncthreads();

    {
        int h = t >> 4, c = t & 15;
        qcat[((size_t)h * 512 + n) * 28 + c] = q[(size_t)n * 192 + t];
        kcat[((size_t)h * 512 + n) * 28 + c] = kvb[(size_t)n * 384 + h * 32 + c] * SC_QK;
    }
    if (t < 144) {
        int h = t / 12;
        float hw = softplus_(hwraw[h]) * SC_HW;
        qcat[((size_t)h * 512 + n) * 28 + 16 + (t - h * 12)] = qp[n * 144 + t];
        kcat[((size_t)h * 512 + n) * 28 + 16 + (t - h * 12)] = kp[n * 144 + t] * hw;
    }
    if (t < 24) {
        int h = t % 12;
        float hw = softplus_(hwraw[h]) * SC_HW;
        const float* src = (t < 12) ? (qp + n * 144 + h * 12) : (kp + n * 144 + h * 12);
        float s = 0.f;
        #pragma unroll
        for (int r = 0; r < 12; ++r) { float v = src[r]; s = fmaf(v, v, s); }
        float* dst = (t < 12) ? qn : kn;
        dst[h * 512 + n] = 0.5f * hw * s;
    }
}

// ---------------------------------------------------------------------------
// Pre-logits GEMM: att[h,i,j] = sc_qk q.k - 0.5 hw |qp-kp|^2 + mask term.
// ---------------------------------------------------------------------------
__global__ __launch_bounds__(256) void qkpt_gemm(
    const float* __restrict__ qcat, const float* __restrict__ kcat,
    const float* __restrict__ qn,   const float* __restrict__ kn,
    const float* __restrict__ mask, float* __restrict__ att)
{
    const int jt = blockIdx.x, it = blockIdx.y, h = blockIdx.z;
    __shared__ float As[28 * 68];
    __shared__ float Bs[28 * 68];
    __shared__ float qn_s[64], kn_s[64], mI[64], mJ[64];

    const int t  = threadIdx.x;
    const int tm = t & 15;
    const int tn = t >> 4;

    const float* Aq = qcat + ((size_t)h * 512 + it * 64) * 28;
    const float* Bk = kcat + ((size_t)h * 512 + jt * 64) * 28;
    for (int idx = t; idx < 448; idx += 256) {
        int row = idx / 7, c4 = idx % 7;
        float4 a4 = *(const float4*)(Aq + row * 28 + c4 * 4);
        As[(c4 * 4 + 0) * 68 + row] = a4.x;
        As[(c4 * 4 + 1) * 68 + row] = a4.y;
        As[(c4 * 4 + 2) * 68 + row] = a4.z;
        As[(c4 * 4 + 3) * 68 + row] = a4.w;
        float4 b4 = *(const float4*)(Bk + row * 28 + c4 * 4);
        Bs[(c4 * 4 + 0) * 68 + row] = b4.x;
        Bs[(c4 * 4 + 1) * 68 + row] = b4.y;
        Bs[(c4 * 4 + 2) * 68 + row] = b4.z;
        Bs[(c4 * 4 + 3) * 68 + row] = b4.w;
    }
    if (t < 64) {
        qn_s[t] = qn[h * 512 + it * 64 + t];
        mI[t]   = mask[it * 64 + t];
    } else if (t < 128) {
        kn_s[t - 64] = kn[h * 512 + jt * 64 + (t - 64)];
        mJ[t - 64]   = mask[jt * 64 + (t - 64)];
    }
    __syncthreads();

    float acc[4][4];
    #pragma unroll
    for (int r = 0; r < 4; ++r)
        #pragma unroll
        for (int c = 0; c < 4; ++c) acc[r][c] = 0.f;

    #pragma unroll
    for (int kk = 0; kk < 28; ++kk) {
        float4 a4 = *(const float4*)(As + kk * 68 + tm * 4);
        float4 b4 = *(const float4*)(Bs + kk * 68 + tn * 4);
        float am[4] = {a4.x, a4.y, a4.z, a4.w};
        float bn[4] = {b4.x, b4.y, b4.z, b4.w};
        #pragma unroll
        for (int r = 0; r < 4; ++r)
            #pragma unroll
            for (int c = 0; c < 4; ++c)
                acc[r][c] = fmaf(am[r], bn[c], acc[r][c]);
    }

    #pragma unroll
    for (int r = 0; r < 4; ++r) {
        const int i_ = it * 64 + tm * 4 + r;
        float* dst = att + ((size_t)h * 512 + i_) * 512 + jt * 64 + tn * 4;
        float4 o;
        float qnr = qn_s[tm * 4 + r], mir = mI[tm * 4 + r];
        o.x = acc[r][0] - qnr - kn_s[tn*4+0] + INF_ * (mir * mJ[tn*4+0] - 1.f);
        o.y = acc[r][1] - qnr - kn_s[tn*4+1] + INF_ * (mir * mJ[tn*4+1] - 1.f);
        o.z = acc[r][2] - qnr - kn_s[tn*4+2] + INF_ * (mir * mJ[tn*4+2] - 1.f);
        o.w = acc[r][3] - qnr - kn_s[tn*4+3] + INF_ * (mir * mJ[tn*4+3] - 1.f);
        *(float4*)dst = o;
    }
}

// ---------------------------------------------------------------------------
// z pass 1: att[h,i,j] += sc_b * (z[i,j,:] . W_b + b_b).  Grid (jt 8, i 512).
// ---------------------------------------------------------------------------
__global__ __launch_bounds__(256) void logits_k(
    const float* __restrict__ z, const float* __restrict__ Wb,
    const float* __restrict__ bb, float* __restrict__ att)
{
    __shared__ float ztile[64 * 132];
    const int jt   = blockIdx.x;
    const int i    = blockIdx.y;
    const int jb   = jt * 64;
    const int t    = threadIdx.x;
    const int lane = t & 63;

    const int h0 = __builtin_amdgcn_readfirstlane((t >> 6) * 3);
    const float bbA = bb[h0], bbB = bb[h0 + 1], bbC = bb[h0 + 2];

    const float4* zsrc = (const float4*)z + ((size_t)i * N_ + jb) * 32;
    #pragma unroll
    for (int k2 = 0; k2 < 8; ++k2) {
        int idx = t + k2 * 256;
        int rr = idx >> 5, c4 = idx & 31;
        *(float4*)(ztile + rr * 132 + c4 * 4) = zsrc[(size_t)rr * 32 + c4];
    }
    __syncthreads();

    float b0 = bbA, b1 = bbB, b2 = bbC;
    const float4* zrow = (const float4*)(ztile + lane * 132);
    #pragma unroll 8
    for (int c4 = 0; c4 < 32; ++c4) {
        float4 z4 = zrow[c4];
        float zc[4] = {z4.x, z4.y, z4.z, z4.w};
        #pragma unroll
        for (int cc = 0; cc < 4; ++cc) {
            const int c = c4 * 4 + cc;
            b0 = fmaf(zc[cc], Wb[c * 12 + h0    ], b0);
            b1 = fmaf(zc[cc], Wb[c * 12 + h0 + 1], b1);
            b2 = fmaf(zc[cc], Wb[c * 12 + h0 + 2], b2);
        }
    }

    const size_t base = ((size_t)h0 * 512 + i) * 512 + jb + lane;
    att[base]              = fmaf(SC_B, b0, att[base]);
    att[base + 262144]     = fmaf(SC_B, b1, att[base + 262144]);
    att[base + 2 * 262144] = fmaf(SC_B, b2, att[base + 2 * 262144]);
}

// ---------------------------------------------------------------------------
// attn_apply: per-i softmax + o + o_pt + point finish + o_pair.
// 512 blocks x 512 threads, 50.7 KB LDS. Probs stay in LDS.
// LDS aliasing contract: pb (o_pair partials) overlays a_s/opt_s/pb_o; all
// reads of the overlaid regions complete before the __syncthreads() that
// precedes the first pb write.
// ---------------------------------------------------------------------------
__global__ __launch_bounds__(512) void attn_apply(
    const float* __restrict__ att, const float* __restrict__ z,
    const float* __restrict__ vcat, const float* __restrict__ rot,
    const float* __restrict__ trans, float* __restrict__ cat)
{
    __shared__ float buf[12672];       // 50688 B
    float* a_s   = buf;                // 12*516 = 6192 (probs)
    float* opt_s = buf + 6192;         // 288   (o_pt staging)
    float* pb_o  = buf + 6480;         // 4*484 = 1936 (o/o_pt partials)
    float* pb    = buf;                // 16*6*132 = 12672 (o_pair partials)

    const int i    = blockIdx.x;
    const int t    = threadIdx.x;
    const int lane = t & 63;

    // ---- 1) load logits ----
    for (int idx = t; idx < 1536; idx += 512) {
        int h = idx >> 7, j4 = idx & 127;
        *(float4*)(a_s + h * 516 + j4 * 4) =
            *((const float4*)att + ((size_t)h * 512 + i) * 128 + j4);
    }
    __syncthreads();

    // ---- 2) softmax: wave w -> head w; waves 0-3 also head 8+w ----
    {
        const int w = t >> 6;
        #pragma unroll
        for (int hh = 0; hh < 2; ++hh) {
            if (hh == 1 && w >= 4) break;
            const int h = (hh == 0) ? w : 8 + w;
            float* row = a_s + h * 516;
            float4 v0 = *(float4*)(row + lane * 8);
            float4 v1 = *(float4*)(row + lane * 8 + 4);
            float m = fmaxf(fmaxf(fmaxf(v0.x, v0.y), fmaxf(v0.z, v0.w)),
                            fmaxf(fmaxf(v1.x, v1.y), fmaxf(v1.z, v1.w)));
            #pragma unroll
            for (int off = 32; off > 0; off >>= 1)
                m = fmaxf(m, __shfl_xor(m, off));
            v0.x = __expf(v0.x - m); v0.y = __expf(v0.y - m);
            v0.z = __expf(v0.z - m); v0.w = __expf(v0.w - m);
            v1.x = __expf(v1.x - m); v1.y = __expf(v1.y - m);
            v1.z = __expf(v1.z - m); v1.w = __expf(v1.w - m);
            float s = v0.x + v0.y + v0.z + v0.w + v1.x + v1.y + v1.z + v1.w;
            #pragma unroll
            for (int off = 32; off > 0; off >>= 1)
                s += __shfl_xor(s, off);
            float inv = 1.f / s;
            v0.x *= inv; v0.y *= inv; v0.z *= inv; v0.w *= inv;
            v1.x *= inv; v1.y *= inv; v1.z *= inv; v1.w *= inv;
            *(float4*)(row + lane * 8)     = v0;
            *(float4*)(row + lane * 8 + 4) = v1;
        }
    }
    __syncthreads();

    // ---- 3) o / o_pt: thread = (col-quad cq, j-quarter jg) ----
    {
        const int jg = t & 3;
        const int cq = t >> 2;          // 0..127
        if (cq < 120) {
            const int col = cq * 4;
            const int h = (col < 192) ? (col >> 4) : ((col - 192) / 24);
            const float* arow = a_s + h * 516;
            const float4* vbase = (const float4*)vcat + cq;
            float4 acc = make_float4(0.f, 0.f, 0.f, 0.f);
            for (int jb = jg * 128; jb < jg * 128 + 128; jb += 4) {
                float4 a4 = *(const float4*)(arow + jb);
                float4 v0 = vbase[(size_t)(jb + 0) * 128];
                float4 v1 = vbase[(size_t)(jb + 1) * 128];
                float4 v2 = vbase[(size_t)(jb + 2) * 128];
                float4 v3 = vbase[(size_t)(jb + 3) * 128];
                acc.x = fmaf(a4.x, v0.x, acc.x);
                acc.y = fmaf(a4.x, v0.y, acc.y);
                acc.z = fmaf(a4.x, v0.z, acc.z);
                acc.w = fmaf(a4.x, v0.w, acc.w);
                acc.x = fmaf(a4.y, v1.x, acc.x);
                acc.y = fmaf(a4.y, v1.y, acc.y);
                acc.z = fmaf(a4.y, v1.z, acc.z);
                acc.w = fmaf(a4.y, v1.w, acc.w);
                acc.x = fmaf(a4.z, v2.x, acc.x);
                acc.y = fmaf(a4.z, v2.y, acc.y);
                acc.z = fmaf(a4.z, v2.z, acc.z);
                acc.w = fmaf(a4.z, v2.w, acc.w);
                acc.x = fmaf(a4.w, v3.x, acc.x);
                acc.y = fmaf(a4.w, v3.y, acc.y);
                acc.z = fmaf(a4.w, v3.z, acc.z);
                acc.w = fmaf(a4.w, v3.w, acc.w);
            }
            *(float4*)(pb_o + jg * 484 + col) = acc;
        }
    }
    __syncthreads();
    if (t < 480) {
        float s = pb_o[t] + pb_o[484 + t] + pb_o[968 + t] + pb_o[1452 + t];
        if (t < 192) cat[(size_t)i * 2112 + t] = s;
        else         opt_s[t - 192] = s;
    }
    __syncthreads();

    // ---- 4) finish points: rot^T (g - trans), norm ----
    if (t < 96) {
        const float* R = rot   + i * 9;
        const float* T = trans + i * 3;
        float g0 = opt_s[t * 3 + 0] - T[0];
        float g1 = opt_s[t * 3 + 1] - T[1];
        float g2 = opt_s[t * 3 + 2] - T[2];
        float x  = R[0]*g0 + R[3]*g1 + R[6]*g2;
        float y  = R[1]*g0 + R[4]*g1 + R[7]*g2;
        float zz = R[2]*g0 + R[5]*g1 + R[8]*g2;
        float nrm = sqrtf(x*x + y*y + zz*zz + EPS_);
        float* cr = cat + (size_t)i * 2112;
        cr[192 + t] = x;
        cr[288 + t] = y;
        cr[384 + t] = zz;
        cr[480 + t] = nrm;
    }
    // no barrier needed: the first pb write below is behind a __syncthreads()

    // ---- 5) o_pair = a . z  (z pass 2, L3-fed) ----
    {
        const int c4 = t & 31;
        const int jg = t >> 5;          // 0..15, 32 j each
        float4 acc[12];
        #pragma unroll
        for (int h = 0; h < 12; ++h) acc[h] = make_float4(0.f, 0.f, 0.f, 0.f);

        const float4* zr = (const float4*)z + (size_t)i * (N_ * 32) + c4;
        #pragma unroll 2
        for (int j4b = 0; j4b < 8; ++j4b) {
            const int jb = jg * 32 + j4b * 4;
            float4 zv[4];
            #pragma unroll
            for (int u = 0; u < 4; ++u) zv[u] = zr[(size_t)(jb + u) * 32];
            #pragma unroll
            for (int h = 0; h < 12; ++h) {
                float4 a4 = *(const float4*)(a_s + h * 516 + jb);
                acc[h].x = fmaf(a4.x, zv[0].x, acc[h].x);
                acc[h].y = fmaf(a4.x, zv[0].y, acc[h].y);
                acc[h].z = fmaf(a4.x, zv[0].z, acc[h].z);
                acc[h].w = fmaf(a4.x, zv[0].w, acc[h].w);
                acc[h].x = fmaf(a4.y, zv[1].x, acc[h].x);
                acc[h].y = fmaf(a4.y, zv[1].y, acc[h].y);
                acc[h].z = fmaf(a4.y, zv[1].z, acc[h].z);
                acc[h].w = fmaf(a4.y, zv[1].w, acc[h].w);
                acc[h].x = fmaf(a4.z, zv[2].x, acc[h].x);
                acc[h].y = fmaf(a4.z, zv[2].y, acc[h].y);
                acc[h].z = fmaf(a4.z, zv[2].z, acc[h].z);
                acc[h].w = fmaf(a4.z, zv[2].w, acc[h].w);
                acc[h].x = fmaf(a4.w, zv[3].x, acc[h].x);
                acc[h].y = fmaf(a4.w, zv[3].y, acc[h].y);
                acc[h].z = fmaf(a4.w, zv[3].z, acc[h].z);
                acc[h].w = fmaf(a4.w, zv[3].w, acc[h].w);
            }
        }

        #pragma unroll
        for (int half = 0; half < 2; ++half) {
            __syncthreads();
            #pragma unroll
            for (int hh = 0; hh < 6; ++hh)
                *(float4*)(pb + (size_t)(jg * 6 + hh) * 132 + c4 * 4) = acc[half * 6 + hh];
            __syncthreads();
            #pragma unroll
            for (int k = 0; k < 2; ++k) {
                const int idx = t + k * 512;          // 0..1023
                if (idx < 768) {
                    const int hh = idx >> 7, c = idx & 127;
                    float s = 0.f;
                    #pragma unroll
                    for (int g = 0; g < 16; ++g)
                        s += pb[(size_t)(g * 6 + hh) * 132 + c];
                    cat[(size_t)i * 2112 + 576 + half * 768 + idx] = s;
                }
            }
        }
    }
}

// ---------------------------------------------------------------------------
// Output GEMM: K=2112 split 11 ways into gpart[kc][512][384], then reduce.
// ---------------------------------------------------------------------------
__global__ __launch_bounds__(256) void gemm_ksplit(
    const float* __restrict__ A, const float* __restrict__ W,
    float* __restrict__ P)
{
    const int kc = blockIdx.z;
    const int m0 = blockIdx.x * 64;
    const int n0 = blockIdx.y * 64;

    __shared__ float As[16 * 68];
    __shared__ float Bs[16 * 68];
    const int t  = threadIdx.x;
    const int tm = t & 15;
    const int tn = t >> 4;

    float acc[4][4];
    #pragma unroll
    for (int r = 0; r < 4; ++r)
        #pragma unroll
        for (int c = 0; c < 4; ++c) acc[r][c] = 0.f;

    const int kbeg = kc * 192;
    for (int k0 = kbeg; k0 < kbeg + 192; k0 += 16) {
        {
            int m = t >> 2, kb = (t & 3) * 4;
            float4 a4 = *(const float4*)(A + (size_t)(m0 + m) * 2112 + k0 + kb);
            As[(kb + 0) * 68 + m] = a4.x;
            As[(kb + 1) * 68 + m] = a4.y;
            As[(kb + 2) * 68 + m] = a4.z;
            As[(kb + 3) * 68 + m] = a4.w;
        }
        {
            int kk = t >> 4, n = (t & 15) * 4;
            float4 b4 = *(const float4*)(W + (size_t)(k0 + kk) * 384 + n0 + n);
            *(float4*)(Bs + kk * 68 + n) = b4;
        }
        __syncthreads();
        #pragma unroll
        for (int kk = 0; kk < 16; ++kk) {
            float4 a4 = *(const float4*)(As + kk * 68 + tm * 4);
            float4 b4 = *(const float4*)(Bs + kk * 68 + tn * 4);
            float am[4] = {a4.x, a4.y, a4.z, a4.w};
            float bn[4] = {b4.x, b4.y, b4.z, b4.w};
            #pragma unroll
            for (int r = 0; r < 4; ++r)
                #pragma unroll
                for (int c = 0; c < 4; ++c)
                    acc[r][c] = fmaf(am[r], bn[c], acc[r][c]);
        }
        __syncthreads();
    }
    float* Pk = P + (size_t)kc * (512 * 384);
    #pragma unroll
    for (int r = 0; r < 4; ++r) {
        int gm = m0 + tm * 4 + r;
        *(float4*)(Pk + (size_t)gm * 384 + n0 + tn * 4) =
            make_float4(acc[r][0], acc[r][1], acc[r][2], acc[r][3]);
    }
}

__global__ __launch_bounds__(256) void reduce_out(
    const float* __restrict__ P, const float* __restrict__ bias,
    float* __restrict__ out)
{
    int idx = blockIdx.x * 256 + threadIdx.x;   // float4 index, 49152 total
    const float4* b4 = (const float4*)bias;
    float4 s = b4[idx % 96];
    const float4* P4 = (const float4*)P;
    #pragma unroll
    for (int g = 0; g < 11; ++g) {
        float4 v = P4[(size_t)g * 49152 + idx];
        s.x += v.x; s.y += v.y; s.z += v.z; s.w += v.w;
    }
    ((float4*)out)[idx] = s;
}

// ---------------------------------------------------------------------------
extern "C" void kernel_launch(void* const* d_in, const int* in_sizes, int n_in,
                              void* d_out, int out_size, void* d_ws, size_t ws_size,
                              hipStream_t stream)
{
    const float* s     = (const float*)d_in[0];
    const float* z     = (const float*)d_in[1];
    const float* rot   = (const float*)d_in[2];
    const float* trans = (const float*)d_in[3];
    const float* mask  = (const float*)d_in[4];
    const float* W_q   = (const float*)d_in[5];
    const float* b_q   = (const float*)d_in[6];
    const float* W_kv  = (const float*)d_in[7];
    const float* b_kv  = (const float*)d_in[8];
    const float* W_qp  = (const float*)d_in[9];
    const float* b_qp  = (const float*)d_in[10];
    const float* W_kvp = (const float*)d_in[11];
    const float* b_kvp = (const float*)d_in[12];
    const float* W_b   = (const float*)d_in[13];
    const float* b_b   = (const float*)d_in[14];
    const float* hw    = (const float*)d_in[15];
    const float* W_out = (const float*)d_in[16];
    const float* b_out = (const float*)d_in[17];
    float* out = (float*)d_out;
    float* ws  = (float*)d_ws;

    float* att   = ws;                       // 3145728
    float* cat   = att   + 3145728;          // 1081344
    float* q     = cat   + 1081344;          // 98304
    float* kvb   = q     + 98304;            // 196608
    float* lqp   = kvb   + 196608;           // 73728
    float* lkvp  = lqp   + 73728;            // 221184
    float* qp    = lkvp  + 221184;           // 73728
    float* kp    = qp    + 73728;            // 73728
    float* vcat  = kp    + 73728;            // 262144
    float* qcat  = vcat  + 262144;           // 172032
    float* kcat  = qcat  + 172032;           // 172032
    float* qn    = kcat  + 172032;           // 6144
    float* kn    = qn    + 6144;             // 6144
    float* gpart = kn    + 6144;             // 2162688

    proj_gemm<<<dim3(8, 7, 4), 256, 0, stream>>>(
        s,
        W_q,   b_q,   q,    192,
        W_kv,  b_kv,  kvb,  384,
        W_qp,  b_qp,  lqp,  144,
        W_kvp, b_kvp, lkvp, 432);
    prep_points<<<512, 192, 0, stream>>>(lqp, lkvp, rot, trans, kvb, q, hw,
                                         qp, kp, vcat, qcat, kcat, qn, kn);
    qkpt_gemm<<<dim3(8, 8, 12), 256, 0, stream>>>(qcat, kcat, qn, kn, mask, att);
    logits_k<<<dim3(8, 512), 256, 0, stream>>>(z, W_b, b_b, att);
    attn_apply<<<512, 512, 0, stream>>>(att, z, vcat, rot, trans, cat);
    gemm_ksplit<<<dim3(8, 6, 11), 256, 0, stream>>>(cat, W_out, gpart);
    reduce_out<<<192, 256, 0, stream>>>(gpart, b_out, out);
}